// Round 2
// baseline (495.314 us; speedup 1.0000x reference)
//
#include <hip/hip_runtime.h>

#define T2 128

// One block per batch element b. 256 threads = 4 waves.
// Thread layout: to = tid>>1 (0..127), h = tid&1 (from-half).
// E = exp(trans[to, h*64 .. h*64+63]) held in 64 VGPRs per thread.
// Scaled-prob domain: q'[to] = (sum_f E[to,f]*q[f]) * exp(feat[t,to]).
// Pair half-dots combined with one __shfl_xor (no LDS, no barrier).
// q double-buffered in LDS -> exactly ONE __syncthreads per step.
// Sum-rescale every 8 steps, folded into next step's ef (no extra barrier);
// a rescale pending at the end cancels and is ignored.
__launch_bounds__(256, 1)
__global__ void crf_fwd(const float* __restrict__ feats,
                        const float* __restrict__ trans,
                        float* __restrict__ out, int S) {
  const int b   = blockIdx.x;
  const int tid = threadIdx.x;
  const int to  = tid >> 1;   // 0..127
  const int h   = tid & 1;    // from-half
  const int wid = tid >> 6;   // wave id 0..3

  __shared__ __align__(16) float qbuf[2][T2];
  __shared__ float red[4];

  // ---- init: E registers
  float E[64];
  {
    const float* trow = trans + to * T2 + h * 64;
#pragma unroll
    for (int i = 0; i < 64; i += 4) {
      float4 tv = *reinterpret_cast<const float4*>(trow + i);
      E[i + 0] = __expf(tv.x);
      E[i + 1] = __expf(tv.y);
      E[i + 2] = __expf(tv.z);
      E[i + 3] = __expf(tv.w);
    }
  }
  const float eend = __expf(trans[(T2 - 2) * T2 + to]);  // exp(trans[END, to])

  // q0 = one-hot at START (= last index)
  if (tid < T2) qbuf[0][tid] = (tid == T2 - 1) ? 1.0f : 0.0f;

  const float* fb = feats + (size_t)b * S * T2;
  float logacc = 0.0f;
  float fn = fb[to];         // feat for step 0
  float ef = __expf(fn);
  float q  = 0.0f;
  int cur = 0;
  __syncthreads();

  for (int t = 0; t < S; ++t) {
    // prefetch feat row for step t+1 (latency hidden under the matvec)
    if (t + 1 < S) fn = fb[(size_t)(t + 1) * T2 + to];

    // ---- half-row dot from LDS broadcast
    const float4* p4 = reinterpret_cast<const float4*>(&qbuf[cur][h * 64]);
    float a0 = 0.0f, a1 = 0.0f, a2 = 0.0f, a3 = 0.0f;
#pragma unroll
    for (int i = 0; i < 16; ++i) {
      float4 pv = p4[i];
      a0 = fmaf(E[4 * i + 0], pv.x, a0);
      a1 = fmaf(E[4 * i + 1], pv.y, a1);
      a2 = fmaf(E[4 * i + 2], pv.z, a2);
      a3 = fmaf(E[4 * i + 3], pv.w, a3);
    }
    float dot = (a0 + a1) + (a2 + a3);
    dot += __shfl_xor(dot, 1);        // combine the two halves in-pair
    q = dot * ef;
    if (h == 0) qbuf[cur ^ 1][to] = q;

    // ---- every 8 steps: block-wide sum of q, piggybacked on the barrier
    if ((t & 7) == 7) {
      float s = q;
#pragma unroll
      for (int off = 2; off < 64; off <<= 1) s += __shfl_xor(s, off);
      if ((tid & 63) == 0) red[wid] = s;   // = sum of this wave's 32 q's
    }

    __syncthreads();                   // the ONE barrier per step
    cur ^= 1;

    // ef for step t+1; apply pending rescale by folding into ef
    ef = __expf(fn);
    if ((t & 7) == 7 && t + 1 < S) {
      float s = red[0] + red[1] + red[2] + red[3];
      ef *= 1.0f / s;
      logacc += __logf(s);
    }
  }

  // ---- epilogue: logZ = log(sum_to q[to]*exp(trans[END,to])) + logacc
  // (q of the final step is live in registers, duplicated across the pair)
  float w = q * eend;
#pragma unroll
  for (int off = 2; off < 64; off <<= 1) w += __shfl_xor(w, off);
  if ((tid & 63) == 0) red[wid] = w;
  __syncthreads();
  if (tid == 0) out[b] = __logf(red[0] + red[1] + red[2] + red[3]) + logacc;
}

extern "C" void kernel_launch(void* const* d_in, const int* in_sizes, int n_in,
                              void* d_out, int out_size, void* d_ws, size_t ws_size,
                              hipStream_t stream) {
  const float* feats = (const float*)d_in[0];
  const float* trans = (const float*)d_in[1];
  float* out = (float*)d_out;
  const int B = out_size;                // 256
  const int S = in_sizes[0] / (B * T2);  // 1024
  crf_fwd<<<dim3(B), dim3(256), 0, stream>>>(feats, trans, out, S);
}

// Round 3
// 454.274 us; speedup vs baseline: 1.0903x; 1.0903x over previous
//
#include <hip/hip_runtime.h>

#define T2 128

typedef __attribute__((ext_vector_type(2))) _Float16 half2_t;

__device__ __forceinline__ float fdot2(unsigned e, unsigned q, float acc) {
  return __builtin_amdgcn_fdot2(__builtin_bit_cast(half2_t, e),
                                __builtin_bit_cast(half2_t, q), acc, false);
}

__device__ __forceinline__ unsigned pk16(float a, float b) {
  half2_t h;
  h.x = (_Float16)a;
  h.y = (_Float16)b;
  return __builtin_bit_cast(unsigned, h);
}

// One WAVE per batch element: 256 blocks x 64 threads, no barriers anywhere.
// Lane l computes outputs l and l+64. q lives in LDS as 64 packed f16x2
// words: word w = (q[w], q[w+64]); E pre-packed in 128 VGPRs to match.
// q'[to] = (sum_f E[to,f]*q[f]) * exp(feat[t,to]) * 2^-8  (fixed scale,
// exact, removed at the end as 8*S*ln2), corrective l1-rescale every 8 steps.
__launch_bounds__(64, 1)
__global__ void crf_fwd(const float* __restrict__ feats,
                        const float* __restrict__ trans,
                        float* __restrict__ out, int S) {
  const int b = blockIdx.x;
  const int l = threadIdx.x;  // 0..63

  __shared__ __align__(16) unsigned qpk[64];

  // ---- pack E rows l and l+64 into registers (f16 pairs (w, w+64))
  unsigned EA[64], EB[64];
  {
    const float* rA = trans + l * T2;
    const float* rB = trans + (l + 64) * T2;
#pragma unroll
    for (int w = 0; w < 64; ++w) {
      EA[w] = pk16(__expf(rA[w]), __expf(rA[w + 64]));
      EB[w] = pk16(__expf(rB[w]), __expf(rB[w + 64]));
    }
  }
  const float eendA = __expf(trans[(T2 - 2) * T2 + l]);
  const float eendB = __expf(trans[(T2 - 2) * T2 + l + 64]);

  // q0 one-hot at START tag (index 127) -> word 63 = (q[63]=0, q[127]=1)
  qpk[l] = (l == 63) ? pk16(0.f, 1.f) : 0u;

  const float* fb = feats + (size_t)b * S * T2 + l;
  float fA = fb[0], fB = fb[64];
  float logacc = 0.f;
  float qa = 0.f, qb = 0.f;

  for (int t = 0; t < S; ++t) {
    // prefetch next step's feats (hidden under this step's dots)
    const float* fn = fb + (size_t)((t + 1 < S) ? t + 1 : t) * T2;
    float nfA = fn[0];
    float nfB = fn[64];

    float efA = __expf(fA) * 0x1p-8f;
    float efB = __expf(fB) * 0x1p-8f;

    float aA0 = 0.f, aA1 = 0.f, aB0 = 0.f, aB1 = 0.f;
    const uint4* q4 = reinterpret_cast<const uint4*>(qpk);
#pragma unroll
    for (int k = 0; k < 16; ++k) {
      uint4 qq = q4[k];
      aA0 = fdot2(EA[4 * k + 0], qq.x, aA0);
      aA1 = fdot2(EA[4 * k + 1], qq.y, aA1);
      aA0 = fdot2(EA[4 * k + 2], qq.z, aA0);
      aA1 = fdot2(EA[4 * k + 3], qq.w, aA1);
      aB0 = fdot2(EB[4 * k + 0], qq.x, aB0);
      aB1 = fdot2(EB[4 * k + 1], qq.y, aB1);
      aB0 = fdot2(EB[4 * k + 2], qq.z, aB0);
      aB1 = fdot2(EB[4 * k + 3], qq.w, aB1);
    }
    qa = (aA0 + aA1) * efA;
    qb = (aB0 + aB1) * efB;

    // corrective rescale every 8 steps (keeps f16 in range, exact logZ)
    if ((t & 7) == 7) {
      float s = qa + qb;
#pragma unroll
      for (int off = 1; off < 64; off <<= 1) s += __shfl_xor(s, off);
      float inv = 1.0f / s;
      qa *= inv;
      qb *= inv;
      logacc += __logf(s);
    }

    qpk[l] = pk16(qa, qb);  // in-order LDS per wave: no barrier needed
    fA = nfA;
    fB = nfB;
  }

  // ---- epilogue: logZ = log(sum q*eend) + logacc + 8*S*ln2
  float w = qa * eendA + qb * eendB;
#pragma unroll
  for (int off = 1; off < 64; off <<= 1) w += __shfl_xor(w, off);
  if (l == 0) out[b] = __logf(w) + logacc + (float)(8 * S) * 0.6931471805599453f;
}

extern "C" void kernel_launch(void* const* d_in, const int* in_sizes, int n_in,
                              void* d_out, int out_size, void* d_ws, size_t ws_size,
                              hipStream_t stream) {
  const float* feats = (const float*)d_in[0];
  const float* trans = (const float*)d_in[1];
  float* out = (float*)d_out;
  const int B = out_size;                // 256
  const int S = in_sizes[0] / (B * T2);  // 1024
  crf_fwd<<<dim3(B), dim3(64), 0, stream>>>(feats, trans, out, S);
}

// Round 6
// 429.558 us; speedup vs baseline: 1.1531x; 1.0575x over previous
//
#include <hip/hip_runtime.h>

#define T2 128
#define NB 16
#define LOG2E 1.44269504088896340736f
#define LN2   0.69314718055994530942f

typedef _Float16 f16;
typedef __attribute__((ext_vector_type(8))) _Float16 f16x8;
typedef __attribute__((ext_vector_type(4))) float f32x4;

// byte offset of q[chain b][from] in a 4KB buffer, XOR-swizzled so the
// per-(g,kk) ds_read_b128 and per-m ds_write_b64 spread across banks
__device__ __forceinline__ int qoff(int b, int from) {
  return ((b << 8) + (from << 1)) ^ ((b & 7) << 4);
}

// 16 blocks x 256 threads. Block handles NB=16 chains; wave w owns output
// rows to = 32w..32w+31 (m-tiles 2w, 2w+1). Per step: read B frags of q from
// LDS, 8 MFMA (16x16x32 f16), multiply by 2^(feat*log2e - 8 + pending_corr),
// pack f16, write next q buffer, ONE raw s_barrier (lgkmcnt only -- feat
// prefetch loads stay in flight across it). l1 correction every 8 steps,
// computed at step t, folded into step t+1's exp2 argument.
__launch_bounds__(256, 1)
__global__ void crf_fwd(const float* __restrict__ feats,
                        const float* __restrict__ trans,
                        float* __restrict__ out, int S) {
  const int tid = threadIdx.x;
  const int w   = tid >> 6;   // wave 0..3
  const int l   = tid & 63;
  const int g   = l >> 4;     // 0..3
  const int c   = l & 15;     // chain within block
  const int b0  = blockIdx.x * NB;

  __shared__ __align__(16) unsigned char qsm[2][4096];
  __shared__ __align__(16) float red[NB][4];
  __shared__ __align__(16) float redE[NB][4];

  // ---- A fragments: E = exp(trans) for this wave's two 16-row M-tiles.
  // k-mapping k = kk*32 + g*8 + j; any bijective error cancels since B uses
  // the same (lane-group, slot) storage mapping.
  f16x8 A[2][4];
#pragma unroll
  for (int mi = 0; mi < 2; ++mi) {
#pragma unroll
    for (int kk = 0; kk < 4; ++kk) {
      const float* r = trans + (size_t)(32 * w + 16 * mi + c) * T2 + kk * 32 + g * 8;
      float4 u0 = *(const float4*)r;
      float4 u1 = *(const float4*)(r + 4);
      f16x8 a;
      a[0] = (f16)__expf(u0.x); a[1] = (f16)__expf(u0.y);
      a[2] = (f16)__expf(u0.z); a[3] = (f16)__expf(u0.w);
      a[4] = (f16)__expf(u1.x); a[5] = (f16)__expf(u1.y);
      a[6] = (f16)__expf(u1.z); a[7] = (f16)__expf(u1.w);
      A[mi][kk] = a;
    }
  }
  // end-transition weights for this lane's 8 C elements (to = 32w+16mi+4g+r)
  float4 eend[2];
#pragma unroll
  for (int mi = 0; mi < 2; ++mi) {
    const float* r = trans + (size_t)(T2 - 2) * T2 + 32 * w + 16 * mi + 4 * g;
    float4 u = *(const float4*)r;
    eend[mi] = make_float4(__expf(u.x), __expf(u.y), __expf(u.z), __expf(u.w));
  }

  // ---- q0 buffer: one-hot at from = 127 (START tag) for all chains.
  // BARRIER between zero-fill and one-hot: the one-hot byte for chain c
  // lives in a 16B block zero-filled by a thread in ANOTHER wave (r5 NaN bug).
  *(uint4*)(qsm[0] + tid * 16) = make_uint4(0, 0, 0, 0);
  __syncthreads();
  if (tid < NB) *(f16*)(qsm[0] + qoff(tid, T2 - 1)) = (f16)1.0f;
  __syncthreads();

  const float* fbase = feats + (size_t)(b0 + c) * S * T2 + 32 * w + 4 * g;
  float4 fcur[2], fnx[2];
  fcur[0] = *(const float4*)(fbase);
  fcur[1] = *(const float4*)(fbase + 16);

  float log2acc = 0.f;
  int cur = 0;
  float qv[2][4] = {};

  for (int t = 0; t < S; ++t) {
    // prefetch next step's feats (stays in flight across the barrier)
    const float* fp = fbase + (size_t)((t + 1 < S) ? t + 1 : t) * T2;
    fnx[0] = *(const float4*)(fp);
    fnx[1] = *(const float4*)(fp + 16);

    // B fragments of q from LDS
    f16x8 B[4];
#pragma unroll
    for (int kk = 0; kk < 4; ++kk) {
      uint4 u = *(const uint4*)(qsm[cur] + qoff(c, kk * 32 + g * 8));
      B[kk] = __builtin_bit_cast(f16x8, u);
    }

    // pending l1 correction (partials written at end of step t-1)
    float lsc = 0.f;
    if ((t & 7) == 0 && t > 0) {
      float4 rv = *(const float4*)&red[c][0];
      float s = (rv.x + rv.y) + (rv.z + rv.w);
      s = fmaxf(s, 1e-35f);  // NaN-cascade guard: pathology -> finite wrong
      float l2 = __builtin_amdgcn_logf(s);
      log2acc += l2;
      lsc = -l2;
    }

    // ef = 2^(feat*log2e - 8 + lsc)
    float bias = lsc - 8.f;
    float ef[2][4];
#pragma unroll
    for (int mi = 0; mi < 2; ++mi) {
      ef[mi][0] = __builtin_amdgcn_exp2f(fmaf(fcur[mi].x, LOG2E, bias));
      ef[mi][1] = __builtin_amdgcn_exp2f(fmaf(fcur[mi].y, LOG2E, bias));
      ef[mi][2] = __builtin_amdgcn_exp2f(fmaf(fcur[mi].z, LOG2E, bias));
      ef[mi][3] = __builtin_amdgcn_exp2f(fmaf(fcur[mi].w, LOG2E, bias));
    }

    // 8 MFMA: C[mi] = sum_kk A[mi][kk] * B[kk]
#pragma unroll
    for (int mi = 0; mi < 2; ++mi) {
      f32x4 acc = {0.f, 0.f, 0.f, 0.f};
#pragma unroll
      for (int kk = 0; kk < 4; ++kk)
        acc = __builtin_amdgcn_mfma_f32_16x16x32_f16(A[mi][kk], B[kk], acc, 0, 0, 0);
      qv[mi][0] = acc[0] * ef[mi][0];
      qv[mi][1] = acc[1] * ef[mi][1];
      qv[mi][2] = acc[2] * ef[mi][2];
      qv[mi][3] = acc[3] * ef[mi][3];
    }

    // every 8th step: per-chain l1 partial -> red (read at t+1 after barrier)
    if ((t & 7) == 7) {
      float p = ((qv[0][0] + qv[0][1]) + (qv[0][2] + qv[0][3]))
              + ((qv[1][0] + qv[1][1]) + (qv[1][2] + qv[1][3]));
      p += __shfl_xor(p, 16);
      p += __shfl_xor(p, 32);
      if (g == 0) red[c][w] = p;
    }

    // pack and write next q buffer
    const int nxt = cur ^ 1;
#pragma unroll
    for (int mi = 0; mi < 2; ++mi) {
      uint2 pw;
      pw.x = __builtin_bit_cast(unsigned,
                __builtin_amdgcn_cvt_pkrtz(qv[mi][0], qv[mi][1]));
      pw.y = __builtin_bit_cast(unsigned,
                __builtin_amdgcn_cvt_pkrtz(qv[mi][2], qv[mi][3]));
      *(uint2*)(qsm[nxt] + qoff(c, 32 * w + 16 * mi + 4 * g)) = pw;
    }

    // raw barrier: drain LDS only, keep global prefetches in flight
    asm volatile("s_waitcnt lgkmcnt(0)" ::: "memory");
    __builtin_amdgcn_s_barrier();
    asm volatile("" ::: "memory");

    cur = nxt;
    fcur[0] = fnx[0];
    fcur[1] = fnx[1];
  }

  // ---- epilogue: Z_c = sum_to q[to,c]*eend[to]; logZ = ln2*(log2 sum + acc + 8S)
  float p = qv[0][0] * eend[0].x + qv[0][1] * eend[0].y +
            qv[0][2] * eend[0].z + qv[0][3] * eend[0].w +
            qv[1][0] * eend[1].x + qv[1][1] * eend[1].y +
            qv[1][2] * eend[1].z + qv[1][3] * eend[1].w;
  p += __shfl_xor(p, 16);
  p += __shfl_xor(p, 32);
  if (g == 0) redE[c][w] = p;
  __syncthreads();
  if (tid < NB) {
    float4 rv = *(const float4*)&redE[tid][0];
    float s = fmaxf((rv.x + rv.y) + (rv.z + rv.w), 1e-35f);
    out[b0 + tid] = (__builtin_amdgcn_logf(s) + log2acc + 8.0f * (float)S) * LN2;
  }
}

extern "C" void kernel_launch(void* const* d_in, const int* in_sizes, int n_in,
                              void* d_out, int out_size, void* d_ws, size_t ws_size,
                              hipStream_t stream) {
  const float* feats = (const float*)d_in[0];
  const float* trans = (const float*)d_in[1];
  float* out = (float*)d_out;
  const int B = out_size;                // 256
  const int S = in_sizes[0] / (B * T2);  // 1024
  crf_fwd<<<dim3(B / NB), dim3(256), 0, stream>>>(feats, trans, out, S);
}